// Round 7
// baseline (253.227 us; speedup 1.0000x reference)
//
#include <hip/hip_runtime.h>
#include <math.h>

typedef short short8 __attribute__((ext_vector_type(8)));
typedef float float4_t __attribute__((ext_vector_type(4)));
typedef unsigned uint2_t __attribute__((ext_vector_type(2)));
typedef unsigned short ushort_t;

#define BH   32
#define N_   2048
#define D_   64
#define NW   (N_ / 64)          // 32 mask words per row
#define NC   (N_ / 64)          // 32 key chunks of 64
#define LDP  72
#define KV_ELEMS (BH * N_ * D_) // 4194304
// d_ws layout (bytes): Kbf [0,8M) | VTswz [8M,16M) | mask [16M,16.5M)
#define OFF_VTS (KV_ELEMS * 2)
#define OFF_MSK (KV_ELEMS * 4)
#define QSCALE 0.18033688f      // 0.125 * log2(e); exp(s/8) == exp2(s*QSCALE)

// natural-order bf16 pair pack (round-half-up), 3 VALU ops
__device__ __forceinline__ unsigned pack_bf16(float a, float b) {
  union { float f; unsigned u; } ua{a}, ub{b};
  return __builtin_amdgcn_perm(ub.u + 0x8000u, ua.u + 0x8000u, 0x07060302u);
}

// ---------- pre-pass: Kbf convert | V transpose+swizzle | adj bitmask ----------
__global__ __launch_bounds__(256) void prep_kernel(
    const float* __restrict__ K, const float* __restrict__ V,
    const int* __restrict__ adj, ushort_t* __restrict__ Kbf,
    ushort_t* __restrict__ VTs, unsigned long long* __restrict__ msk) {
  __shared__ float Vs[64 * 68];          // [key][d], stride 68 (16B rows)
  const int b = blockIdx.x, t = threadIdx.x;

  if (b < 1024) {                        // K fp32 -> bf16, 16 elems/thread
    const int idx = (b * 256 + t) * 16;
    const float* kp = K + idx;
    float4_t f0 = *(const float4_t*)(kp);
    float4_t f1 = *(const float4_t*)(kp + 4);
    float4_t f2 = *(const float4_t*)(kp + 8);
    float4_t f3 = *(const float4_t*)(kp + 12);
    union { short8 s; unsigned u[4]; } h;
    h.u[0] = pack_bf16(f0[0], f0[1]); h.u[1] = pack_bf16(f0[2], f0[3]);
    h.u[2] = pack_bf16(f1[0], f1[1]); h.u[3] = pack_bf16(f1[2], f1[3]);
    *(short8*)(Kbf + idx) = h.s;
    h.u[0] = pack_bf16(f2[0], f2[1]); h.u[1] = pack_bf16(f2[2], f2[3]);
    h.u[2] = pack_bf16(f3[0], f3[1]); h.u[3] = pack_bf16(f3[2], f3[3]);
    *(short8*)(Kbf + idx + 8) = h.s;
  } else if (b < 2048) {                 // V -> VTswz[bh][d][kb+key'], bf16
    const int blk = b - 1024;            // 32 bh x 32 key-chunks
    const int bh = blk & 31, kc = blk >> 5, kb = kc * 64;
    const int vbase = bh * (N_ * D_);
#pragma unroll
    for (int i = 0; i < 4; ++i) {        // stage 64x64 fp32 tile, coalesced
      int idx = i * 256 + t;
      int key = idx >> 4, c4 = (idx & 15) * 4;
      *(float4_t*)&Vs[key * 68 + c4] =
          *(const float4_t*)(V + vbase + (kb + key) * D_ + c4);
    }
    __syncthreads();
#pragma unroll
    for (int i = 0; i < 2; ++i) {        // write rows of VT, key'-swizzled
      int idx = i * 256 + t;
      int d = idx >> 3, kq = (idx & 7) * 8;
      float v[8];
#pragma unroll
      for (int j = 0; j < 8; ++j) {
        int kp_ = kq + j;
        int key = 16 * (kp_ & 3) + (kp_ >> 2);   // inverse of key'=4*(key&15)+(key>>4)
        v[j] = Vs[key * 68 + d];
      }
      union { short8 s; unsigned u[4]; } h;
      h.u[0] = pack_bf16(v[0], v[1]); h.u[1] = pack_bf16(v[2], v[3]);
      h.u[2] = pack_bf16(v[4], v[5]); h.u[3] = pack_bf16(v[6], v[7]);
      *(short8*)(VTs + vbase + d * N_ + kb + kq) = h.s;
    }
  } else {                               // adj -> bitmask, ballot per word
    const int wv = (b - 2048) * 4 + (t >> 6);   // 1024 mask waves
    const int lane = t & 63;
#pragma unroll 4
    for (int i = 0; i < 64; ++i) {
      int word = wv * 64 + i;
      int row = word >> 5, wc = word & 31;
      int a = adj[row * N_ + wc * 64 + lane];
      unsigned long long m = __ballot(a > 0);
      if (lane == 0) msk[word] = m;
    }
  }
}

// ---------- main: barrier-free flash attention, direct fragment loads ----------
__global__ __launch_bounds__(256) void attn_main(
    const float* __restrict__ Q, const ushort_t* __restrict__ Kbf,
    const ushort_t* __restrict__ VTs, const unsigned long long* __restrict__ msk,
    float* __restrict__ O) {
  __shared__ __align__(16) ushort_t lds_p[4][2][16 * LDP];  // wave-private P

  const int tid  = threadIdx.x;
  const int w    = tid >> 6;
  const int lane = tid & 63;
  const int quad = lane >> 4;
  const int l16  = lane & 15;
  const int bh   = blockIdx.x & (BH - 1);   // same-bh blocks -> same XCD L2
  const int grp  = blockIdx.x >> 5;         // 0..15
  const int tile = grp * 4 + w;             // 0..63 per bh
  const int qrow0 = tile * 32;              // 32 q-rows per wave
  const int base = bh * (N_ * D_);
  const ushort_t* Kb = Kbf + base;
  const ushort_t* Vb = VTs + base;

  // Q fragments x2 groups, scale folded (A-layout m=l16, k=ks*32+quad*8+j)
  short8 qf[2][2];
#pragma unroll
  for (int qg = 0; qg < 2; ++qg)
#pragma unroll
    for (int ks = 0; ks < 2; ++ks) {
      const float* qp = Q + base + (qrow0 + qg * 16 + l16) * D_ + ks * 32 + quad * 8;
      float4_t f0 = *(const float4_t*)(qp);
      float4_t f1 = *(const float4_t*)(qp + 4);
      union { short8 s; unsigned u[4]; } h;
      h.u[0] = pack_bf16(f0[0] * QSCALE, f0[1] * QSCALE);
      h.u[1] = pack_bf16(f0[2] * QSCALE, f0[3] * QSCALE);
      h.u[2] = pack_bf16(f1[0] * QSCALE, f1[1] * QSCALE);
      h.u[3] = pack_bf16(f1[2] * QSCALE, f1[3] * QSCALE);
      qf[qg][ks] = h.s;
    }

  float4_t oacc[2][4];
  float lsum[2][4];
#pragma unroll
  for (int qg = 0; qg < 2; ++qg) {
#pragma unroll
    for (int dt = 0; dt < 4; ++dt) oacc[qg][dt] = (float4_t){0.f, 0.f, 0.f, 0.f};
#pragma unroll
    for (int r = 0; r < 4; ++r) lsum[qg][r] = 0.f;
  }

  for (int c = 0; c < NC; ++c) {
    const int kb = c * 64;

    // K B-fragments: direct 16B global loads (rows of K)
    short8 kf[4][2];
#pragma unroll
    for (int nt = 0; nt < 4; ++nt)
#pragma unroll
      for (int ks = 0; ks < 2; ++ks)
        kf[nt][ks] = *(const short8*)(Kb + (kb + nt * 16 + l16) * D_ + ks * 32 + quad * 8);

    // V A?B-fragments too: issue early to hide L2 latency under exp work
    short8 vf[4][2];
#pragma unroll
    for (int dt = 0; dt < 4; ++dt)
#pragma unroll
      for (int ks = 0; ks < 2; ++ks)
        vf[dt][ks] = *(const short8*)(Vb + (dt * 16 + l16) * N_ + kb + ks * 32 + quad * 8);

    // S = (Q*scale) K^T
    float4_t sacc[2][4];
#pragma unroll
    for (int qg = 0; qg < 2; ++qg)
#pragma unroll
      for (int nt = 0; nt < 4; ++nt) {
        float4_t acc = (float4_t){0.f, 0.f, 0.f, 0.f};
#pragma unroll
        for (int ks = 0; ks < 2; ++ks)
          acc = __builtin_amdgcn_mfma_f32_16x16x32_bf16(qf[qg][ks], kf[nt][ks], acc, 0, 0, 0);
        sacc[qg][nt] = acc;
      }

    // mask bits + p = exp2(s) -> wave-private LDS (A-layout, key'-swizzled)
#pragma unroll
    for (int qg = 0; qg < 2; ++qg) {
      const int qrowq = qrow0 + qg * 16 + quad * 4;
#pragma unroll
      for (int r = 0; r < 4; ++r) {
        unsigned long long m = msk[(qrowq + r) * NW + c];
        unsigned long long sh = m >> l16;   // bits 0,16,32,48 = keys l16+16nt
        unsigned lo = (unsigned)sh, hi = (unsigned)(sh >> 32);
        float p0 = (lo & 1u)        ? exp2f(sacc[qg][0][r]) : 0.f;
        float p1 = (lo & 0x10000u)  ? exp2f(sacc[qg][1][r]) : 0.f;
        float p2 = (hi & 1u)        ? exp2f(sacc[qg][2][r]) : 0.f;
        float p3 = (hi & 0x10000u)  ? exp2f(sacc[qg][3][r]) : 0.f;
        lsum[qg][r] += (p0 + p1) + (p2 + p3);
        uint2_t d2;
        d2.x = pack_bf16(p0, p1);
        d2.y = pack_bf16(p2, p3);
        *(uint2_t*)&lds_p[w][qg][(quad * 4 + r) * LDP + (l16 << 2)] = d2;
      }
    }
    // no barrier: wave-private (compiler orders via lgkmcnt)

    // O += P V  (P A-frag from LDS, V B-frag already in regs)
#pragma unroll
    for (int qg = 0; qg < 2; ++qg)
#pragma unroll
      for (int ks = 0; ks < 2; ++ks) {
        short8 pf = *(const short8*)&lds_p[w][qg][l16 * LDP + ks * 32 + quad * 8];
#pragma unroll
        for (int dt = 0; dt < 4; ++dt)
          oacc[qg][dt] = __builtin_amdgcn_mfma_f32_16x16x32_bf16(pf, vf[dt][ks], oacc[qg][dt], 0, 0, 0);
      }
  }

  // epilogue: 16-lane row-sum reduction, divide, store fp32
#pragma unroll
  for (int qg = 0; qg < 2; ++qg)
#pragma unroll
    for (int r = 0; r < 4; ++r) {
      float l = lsum[qg][r];
      l += __shfl_xor(l, 1);
      l += __shfl_xor(l, 2);
      l += __shfl_xor(l, 4);
      l += __shfl_xor(l, 8);
      float inv = 1.f / l;
      int qi = qrow0 + qg * 16 + quad * 4 + r;
#pragma unroll
      for (int dt = 0; dt < 4; ++dt)
        O[base + qi * D_ + dt * 16 + l16] = oacc[qg][dt][r] * inv;
    }
}

extern "C" void kernel_launch(void* const* d_in, const int* in_sizes, int n_in,
                              void* d_out, int out_size, void* d_ws, size_t ws_size,
                              hipStream_t stream) {
  const float* Q  = (const float*)d_in[0];
  const float* K  = (const float*)d_in[1];
  const float* V  = (const float*)d_in[2];
  const int* adj  = (const int*)d_in[3];
  float* O        = (float*)d_out;
  ushort_t* Kbf   = (ushort_t*)d_ws;
  ushort_t* VTs   = (ushort_t*)((char*)d_ws + OFF_VTS);
  unsigned long long* msk = (unsigned long long*)((char*)d_ws + OFF_MSK);

  prep_kernel<<<2304, 256, 0, stream>>>(K, V, adj, Kbf, VTs, msk);
  attn_main<<<512, 256, 0, stream>>>(Q, Kbf, VTs, msk, O);
}

// Round 8
// 188.808 us; speedup vs baseline: 1.3412x; 1.3412x over previous
//
#include <hip/hip_runtime.h>
#include <math.h>

typedef short short8 __attribute__((ext_vector_type(8)));
typedef float float4_t __attribute__((ext_vector_type(4)));
typedef unsigned uint2_t __attribute__((ext_vector_type(2)));
typedef unsigned short ushort_t;

#define BH   32
#define N_   2048
#define D_   64
#define NCH  32                 // key chunks of 64
#define LDP  72
#define KV_ELEMS (BH * N_ * D_)
// d_ws: Kf [0,8M) | Vf [8M,16M) | msk [16M,16.5M)   (r7 proved ws >= 16.5MB)
#define OFF_VF  (KV_ELEMS * 2)
#define OFF_MSK (KV_ELEMS * 4)
#define QSCALE 0.18033688f      // 0.125*log2(e): exp(s/8) == exp2(s*QSCALE)

// natural-order bf16 pair pack (round-half-up), 3 VALU ops
__device__ __forceinline__ unsigned pack_bf16(float a, float b) {
  union { float f; unsigned u; } ua{a}, ub{b};
  return __builtin_amdgcn_perm(ub.u + 0x8000u, ua.u + 0x8000u, 0x07060302u);
}

// ---------------- prep: fragment-linear Kf/Vf (bf16) + adj bitmask ----------------
// Unit u = g*64+lane (16B). K: g=ks*4+nt, data = K[c*64+nt*16+l16][ks*32+quad*8+j].
// V: g=ks*4+dt, data = V[key_j][dt*16+l16], key_j = 16*(j&3)+ks*8+quad*2+(j>>2)
//    (key' = 4*(key&15)+(key>>4) swizzle, matching the P-layout proven in r5-r7).
__global__ __launch_bounds__(256) void prep_kernel(
    const float* __restrict__ K, const float* __restrict__ V,
    const int* __restrict__ adj, ushort_t* __restrict__ Kf,
    ushort_t* __restrict__ Vf, unsigned long long* __restrict__ msk) {
  __shared__ __align__(16) float Tc[64 * 68];
  const int blk = blockIdx.x, t = threadIdx.x;

  if (blk < 2048) {                       // K (0..1023) and V (1024..2047)
    const bool isK = blk < 1024;
    const int b = isK ? blk : blk - 1024; // b = bh*32 + c
    const float* src = (isK ? K : V) + (b >> 5) * (N_ * D_) + (b & 31) * 64 * D_;
#pragma unroll
    for (int i = 0; i < 4; ++i) {         // stage 64x64 f32, coalesced
      int idx = i * 256 + t;
      int row = idx >> 4, c4 = (idx & 15) * 4;
      *(float4_t*)&Tc[row * 68 + c4] = *(const float4_t*)(src + row * D_ + c4);
    }
    __syncthreads();
    ushort_t* dst = (isK ? Kf : Vf) + b * 4096;   // 512 units * 8 ushorts
#pragma unroll
    for (int e = 0; e < 2; ++e) {
      int u = t * 2 + e;
      int g = u >> 6, lane = u & 63;
      int ks = g >> 2, quad = lane >> 4, l16 = lane & 15;
      float v[8];
      if (isK) {
        int nt = g & 3;
        const float* rp = &Tc[(nt * 16 + l16) * 68 + ks * 32 + quad * 8];
        float4_t a = *(const float4_t*)(rp);
        float4_t bq = *(const float4_t*)(rp + 4);
#pragma unroll
        for (int j = 0; j < 4; ++j) { v[j] = a[j]; v[4 + j] = bq[j]; }
      } else {
        int dt = g & 3, d = dt * 16 + l16;
#pragma unroll
        for (int j = 0; j < 8; ++j) {
          int key = 16 * (j & 3) + ks * 8 + quad * 2 + (j >> 2);
          v[j] = Tc[key * 68 + d];
        }
      }
      union { short8 s; unsigned u4[4]; } h;
      h.u4[0] = pack_bf16(v[0], v[1]); h.u4[1] = pack_bf16(v[2], v[3]);
      h.u4[2] = pack_bf16(v[4], v[5]); h.u4[3] = pack_bf16(v[6], v[7]);
      *(short8*)(dst + u * 8) = h.s;    // coalesced b128 write
    }
  } else {                                // adj bitmask: one wave per row
    const int row = (blk - 2048) * 4 + (t >> 6);
    const int lane = t & 63;
    unsigned long long keep = 0;
#pragma unroll 8
    for (int i = 0; i < 32; ++i) {
      int a = adj[row * N_ + i * 64 + lane];
      unsigned long long b = __ballot(a > 0);
      if (lane == i) keep = b;
    }
    if (lane < 32) msk[row * 32 + lane] = keep;
  }
}

// ---------------- main: 128 threads = 2 waves x 32 Q-rows, LDS-staged ----------------
__global__ __launch_bounds__(128) void attn_main(
    const float* __restrict__ Q, const ushort_t* __restrict__ Kf,
    const ushort_t* __restrict__ Vf, const unsigned long long* __restrict__ msk,
    float* __restrict__ O) {
  __shared__ __align__(16) ushort_t kbuf[512 * 8];          // fragment-linear
  __shared__ __align__(16) ushort_t vbuf[512 * 8];
  __shared__ __align__(16) ushort_t lds_p[2][2][16 * LDP];  // wave-private P

  const int t    = threadIdx.x;
  const int w    = t >> 6;
  const int lane = t & 63;
  const int quad = lane >> 4;
  const int l16  = lane & 15;
  const int bh   = blockIdx.x & (BH - 1);   // same-bh -> same XCD L2
  const int qt   = blockIdx.x >> 5;
  const int base = bh * (N_ * D_);
  const int qrow0 = qt * 64 + w * 32;       // this wave's 32 rows

  const ushort_t* Kfb = Kf + (bh * 32) * 4096;
  const ushort_t* Vfb = Vf + (bh * 32) * 4096;

  // Q fragments, QSCALE folded (A-layout m=l16, k=ks*32+quad*8+j)
  short8 qf[2][2];
#pragma unroll
  for (int qg = 0; qg < 2; ++qg)
#pragma unroll
    for (int ks = 0; ks < 2; ++ks) {
      const float* qp = Q + base + (qrow0 + qg * 16 + l16) * D_ + ks * 32 + quad * 8;
      float4_t f0 = *(const float4_t*)(qp);
      float4_t f1 = *(const float4_t*)(qp + 4);
      union { short8 s; unsigned u[4]; } h;
      h.u[0] = pack_bf16(f0[0] * QSCALE, f0[1] * QSCALE);
      h.u[1] = pack_bf16(f0[2] * QSCALE, f0[3] * QSCALE);
      h.u[2] = pack_bf16(f1[0] * QSCALE, f1[1] * QSCALE);
      h.u[3] = pack_bf16(f1[2] * QSCALE, f1[3] * QSCALE);
      qf[qg][ks] = h.s;
    }

  float4_t oacc[2][4];
  float lsum[2][4];
#pragma unroll
  for (int qg = 0; qg < 2; ++qg) {
#pragma unroll
    for (int dt = 0; dt < 4; ++dt) oacc[qg][dt] = (float4_t){0.f, 0.f, 0.f, 0.f};
#pragma unroll
    for (int r = 0; r < 4; ++r) lsum[qg][r] = 0.f;
  }

  for (int c = 0; c < NCH; ++c) {
    __syncthreads();                      // prev chunk's LDS reads done

    // ---- stage: 16KB bf16, lane-linear coalesced, no conversion ----
    const ushort_t* kg = Kfb + c * 4096;
    const ushort_t* vg = Vfb + c * 4096;
#pragma unroll
    for (int i = 0; i < 4; ++i) {
      int u = i * 128 + t;
      *(short8*)(kbuf + u * 8) = *(const short8*)(kg + u * 8);
      *(short8*)(vbuf + u * 8) = *(const short8*)(vg + u * 8);
    }
    __syncthreads();

    // ---- fragments from LDS (each feeds 2 MFMAs via qg reuse) ----
    short8 kf[4][2], vf[4][2];
#pragma unroll
    for (int nt = 0; nt < 4; ++nt)
#pragma unroll
      for (int ks = 0; ks < 2; ++ks) {
        kf[nt][ks] = *(const short8*)(kbuf + ((ks * 4 + nt) * 64 + lane) * 8);
        vf[nt][ks] = *(const short8*)(vbuf + ((ks * 4 + nt) * 64 + lane) * 8);
      }

    // ---- S = (Q*scale) K^T ----
    float4_t sacc[2][4];
#pragma unroll
    for (int qg = 0; qg < 2; ++qg)
#pragma unroll
      for (int nt = 0; nt < 4; ++nt) {
        float4_t acc = (float4_t){0.f, 0.f, 0.f, 0.f};
#pragma unroll
        for (int ks = 0; ks < 2; ++ks)
          acc = __builtin_amdgcn_mfma_f32_16x16x32_bf16(qf[qg][ks], kf[nt][ks], acc, 0, 0, 0);
        sacc[qg][nt] = acc;
      }

    // ---- p = exp2(s) masked; P -> wave-private LDS (A-layout, key') ----
#pragma unroll
    for (int qg = 0; qg < 2; ++qg) {
      const int qrowq = qrow0 + qg * 16 + quad * 4;
#pragma unroll
      for (int r = 0; r < 4; ++r) {
        unsigned long long m = msk[(qrowq + r) * 32 + c];
        unsigned long long sh = m >> l16;
        unsigned lo = (unsigned)sh, hi = (unsigned)(sh >> 32);
        float p0 = (lo & 1u)       ? exp2f(sacc[qg][0][r]) : 0.f;
        float p1 = (lo & 0x10000u) ? exp2f(sacc[qg][1][r]) : 0.f;
        float p2 = (hi & 1u)       ? exp2f(sacc[qg][2][r]) : 0.f;
        float p3 = (hi & 0x10000u) ? exp2f(sacc[qg][3][r]) : 0.f;
        lsum[qg][r] += (p0 + p1) + (p2 + p3);
        uint2_t d2;
        d2.x = pack_bf16(p0, p1);
        d2.y = pack_bf16(p2, p3);
        *(uint2_t*)&lds_p[w][qg][(quad * 4 + r) * LDP + (l16 << 2)] = d2;
      }
    }
    // no barrier: wave-private, ordered by lgkmcnt

    // ---- O += P V ----
#pragma unroll
    for (int qg = 0; qg < 2; ++qg)
#pragma unroll
      for (int ks = 0; ks < 2; ++ks) {
        short8 pf = *(const short8*)&lds_p[w][qg][l16 * LDP + ks * 32 + quad * 8];
#pragma unroll
        for (int dt = 0; dt < 4; ++dt)
          oacc[qg][dt] = __builtin_amdgcn_mfma_f32_16x16x32_bf16(pf, vf[dt][ks], oacc[qg][dt], 0, 0, 0);
      }
  }

  // ---- epilogue ----
#pragma unroll
  for (int qg = 0; qg < 2; ++qg)
#pragma unroll
    for (int r = 0; r < 4; ++r) {
      float l = lsum[qg][r];
      l += __shfl_xor(l, 1);
      l += __shfl_xor(l, 2);
      l += __shfl_xor(l, 4);
      l += __shfl_xor(l, 8);
      float inv = 1.f / l;
      int qi = qrow0 + qg * 16 + quad * 4 + r;
#pragma unroll
      for (int dt = 0; dt < 4; ++dt)
        O[base + qi * D_ + dt * 16 + l16] = oacc[qg][dt][r] * inv;
    }
}

extern "C" void kernel_launch(void* const* d_in, const int* in_sizes, int n_in,
                              void* d_out, int out_size, void* d_ws, size_t ws_size,
                              hipStream_t stream) {
  const float* Q  = (const float*)d_in[0];
  const float* K  = (const float*)d_in[1];
  const float* V  = (const float*)d_in[2];
  const int* adj  = (const int*)d_in[3];
  float* O        = (float*)d_out;
  ushort_t* Kf    = (ushort_t*)d_ws;
  ushort_t* Vf    = (ushort_t*)((char*)d_ws + OFF_VF);
  unsigned long long* msk = (unsigned long long*)((char*)d_ws + OFF_MSK);

  prep_kernel<<<2560, 256, 0, stream>>>(K, V, adj, Kf, Vf, msk);
  attn_main<<<1024, 128, 0, stream>>>(Q, Kf, Vf, msk, O);
}

// Round 9
// 188.712 us; speedup vs baseline: 1.3419x; 1.0005x over previous
//
#include <hip/hip_runtime.h>
#include <math.h>

typedef short short8 __attribute__((ext_vector_type(8)));
typedef float float4_t __attribute__((ext_vector_type(4)));
typedef unsigned uint2_t __attribute__((ext_vector_type(2)));
typedef unsigned short ushort_t;

#define BH   32
#define N_   2048
#define D_   64
#define NCH  32
#define LDP  72
#define KV_ELEMS (BH * N_ * D_)
// d_ws: Kf [0,8M) | Vf [8M,16M) | msk [16M,16.5M)
#define OFF_VF  (KV_ELEMS * 2)
#define OFF_MSK (KV_ELEMS * 4)
#define QSCALE 0.18033688f      // 0.125*log2(e): exp(s/8) == exp2(s*QSCALE)

__device__ __forceinline__ unsigned pack_bf16(float a, float b) {
  union { float f; unsigned u; } ua{a}, ub{b};
  return __builtin_amdgcn_perm(ub.u + 0x8000u, ua.u + 0x8000u, 0x07060302u);
}

// ---------------- prep (unchanged from r8, verified): fragment-linear Kf/Vf + bitmask ----------------
__global__ __launch_bounds__(256) void prep_kernel(
    const float* __restrict__ K, const float* __restrict__ V,
    const int* __restrict__ adj, ushort_t* __restrict__ Kf,
    ushort_t* __restrict__ Vf, unsigned long long* __restrict__ msk) {
  __shared__ __align__(16) float Tc[64 * 68];
  const int blk = blockIdx.x, t = threadIdx.x;

  if (blk < 2048) {
    const bool isK = blk < 1024;
    const int b = isK ? blk : blk - 1024;
    const float* src = (isK ? K : V) + (b >> 5) * (N_ * D_) + (b & 31) * 64 * D_;
#pragma unroll
    for (int i = 0; i < 4; ++i) {
      int idx = i * 256 + t;
      int row = idx >> 4, c4 = (idx & 15) * 4;
      *(float4_t*)&Tc[row * 68 + c4] = *(const float4_t*)(src + row * D_ + c4);
    }
    __syncthreads();
    ushort_t* dst = (isK ? Kf : Vf) + b * 4096;
#pragma unroll
    for (int e = 0; e < 2; ++e) {
      int u = t * 2 + e;
      int g = u >> 6, lane = u & 63;
      int ks = g >> 2, quad = lane >> 4, l16 = lane & 15;
      float v[8];
      if (isK) {
        int nt = g & 3;
        const float* rp = &Tc[(nt * 16 + l16) * 68 + ks * 32 + quad * 8];
        float4_t a = *(const float4_t*)(rp);
        float4_t bq = *(const float4_t*)(rp + 4);
#pragma unroll
        for (int j = 0; j < 4; ++j) { v[j] = a[j]; v[4 + j] = bq[j]; }
      } else {
        int dt = g & 3, d = dt * 16 + l16;
#pragma unroll
        for (int j = 0; j < 8; ++j) {
          int key = 16 * (j & 3) + ks * 8 + quad * 2 + (j >> 2);
          v[j] = Tc[key * 68 + d];
        }
      }
      union { short8 s; unsigned u4[4]; } h;
      h.u4[0] = pack_bf16(v[0], v[1]); h.u4[1] = pack_bf16(v[2], v[3]);
      h.u4[2] = pack_bf16(v[4], v[5]); h.u4[3] = pack_bf16(v[6], v[7]);
      *(short8*)(dst + u * 8) = h.s;
    }
  } else {
    const int row = (blk - 2048) * 4 + (t >> 6);
    const int lane = t & 63;
    unsigned long long keep = 0;
#pragma unroll 8
    for (int i = 0; i < 32; ++i) {
      int a = adj[row * N_ + i * 64 + lane];
      unsigned long long b = __ballot(a > 0);
      if (lane == i) keep = b;
    }
    if (lane < 32) msk[row * 32 + lane] = keep;
  }
}

// -------- main: barrier-free, 16 rows/wave, direct coalesced L2 fragment loads --------
__global__ __launch_bounds__(256, 4) void attn_main(
    const float* __restrict__ Q, const ushort_t* __restrict__ Kf,
    const ushort_t* __restrict__ Vf, const unsigned long long* __restrict__ msk,
    float* __restrict__ O) {
  __shared__ __align__(16) ushort_t lds_p[4][16 * LDP];  // wave-private P only

  const int t    = threadIdx.x;
  const int w    = t >> 6;
  const int lane = t & 63;
  const int quad = lane >> 4;
  const int l16  = lane & 15;
  const int bh   = blockIdx.x & (BH - 1);   // same-bh -> L2 sharing
  const int qt   = blockIdx.x >> 5;
  const int base = bh * (N_ * D_);
  const int qrow0 = qt * 64 + w * 16;       // 16 rows per wave

  const ushort_t* Kfb = Kf + (bh * 32) * 4096;
  const ushort_t* Vfb = Vf + (bh * 32) * 4096;
  const unsigned long long* mrow = msk + (qrow0 + quad * 4) * 32;

  // Q fragments, QSCALE folded (A-layout m=l16, k=ks*32+quad*8+j)
  short8 qf[2];
#pragma unroll
  for (int ks = 0; ks < 2; ++ks) {
    const float* qp = Q + base + (qrow0 + l16) * D_ + ks * 32 + quad * 8;
    float4_t f0 = *(const float4_t*)(qp);
    float4_t f1 = *(const float4_t*)(qp + 4);
    union { short8 s; unsigned u[4]; } h;
    h.u[0] = pack_bf16(f0[0] * QSCALE, f0[1] * QSCALE);
    h.u[1] = pack_bf16(f0[2] * QSCALE, f0[3] * QSCALE);
    h.u[2] = pack_bf16(f1[0] * QSCALE, f1[1] * QSCALE);
    h.u[3] = pack_bf16(f1[2] * QSCALE, f1[3] * QSCALE);
    qf[ks] = h.s;
  }

  float4_t oacc[4];
  float lsum[4];
#pragma unroll
  for (int dt = 0; dt < 4; ++dt) oacc[dt] = (float4_t){0.f, 0.f, 0.f, 0.f};
#pragma unroll
  for (int r = 0; r < 4; ++r) lsum[r] = 0.f;

  const int fo = lane * 8;   // lane-linear fragment offset (coalesced 16B/lane)

  for (int c = 0; c < NCH; ++c) {
    const ushort_t* kg = Kfb + c * 4096;
    const ushort_t* vg = Vfb + c * 4096;

    // hoist mask words (L2-broadcast loads) to hide latency under MFMAs
    unsigned long long mw[4];
#pragma unroll
    for (int r = 0; r < 4; ++r) mw[r] = mrow[r * 32 + c];

    // ---- S = (Q*scale) K^T : direct global B-fragments ----
    float4_t sacc[4];
#pragma unroll
    for (int nt = 0; nt < 4; ++nt) sacc[nt] = (float4_t){0.f, 0.f, 0.f, 0.f};
#pragma unroll
    for (int ks = 0; ks < 2; ++ks) {
      short8 kfr[4];
#pragma unroll
      for (int nt = 0; nt < 4; ++nt)
        kfr[nt] = *(const short8*)(kg + (ks * 4 + nt) * 512 + fo);
#pragma unroll
      for (int nt = 0; nt < 4; ++nt)
        sacc[nt] = __builtin_amdgcn_mfma_f32_16x16x32_bf16(qf[ks], kfr[nt], sacc[nt], 0, 0, 0);
    }

    // ---- p = exp2(s) masked; P -> wave-private LDS (A-layout, key') ----
#pragma unroll
    for (int r = 0; r < 4; ++r) {
      unsigned long long sh = mw[r] >> l16;
      unsigned lo = (unsigned)sh, hi = (unsigned)(sh >> 32);
      float p0 = (lo & 1u)       ? exp2f(sacc[0][r]) : 0.f;
      float p1 = (lo & 0x10000u) ? exp2f(sacc[1][r]) : 0.f;
      float p2 = (hi & 1u)       ? exp2f(sacc[2][r]) : 0.f;
      float p3 = (hi & 0x10000u) ? exp2f(sacc[3][r]) : 0.f;
      lsum[r] += (p0 + p1) + (p2 + p3);
      uint2_t d2;
      d2.x = pack_bf16(p0, p1);
      d2.y = pack_bf16(p2, p3);
      *(uint2_t*)&lds_p[w][(quad * 4 + r) * LDP + (l16 << 2)] = d2;
    }
    // no barrier: wave-private, ordered by lgkmcnt

    // ---- O += P V : direct global B-fragments ----
#pragma unroll
    for (int ks = 0; ks < 2; ++ks) {
      short8 vfr[4];
#pragma unroll
      for (int dt = 0; dt < 4; ++dt)
        vfr[dt] = *(const short8*)(vg + (ks * 4 + dt) * 512 + fo);
      short8 pf = *(const short8*)&lds_p[w][l16 * LDP + ks * 32 + quad * 8];
#pragma unroll
      for (int dt = 0; dt < 4; ++dt)
        oacc[dt] = __builtin_amdgcn_mfma_f32_16x16x32_bf16(pf, vfr[dt], oacc[dt], 0, 0, 0);
    }
  }

  // ---- epilogue: 16-lane row-sum reduction, divide, fp32 store ----
#pragma unroll
  for (int r = 0; r < 4; ++r) {
    float l = lsum[r];
    l += __shfl_xor(l, 1);
    l += __shfl_xor(l, 2);
    l += __shfl_xor(l, 4);
    l += __shfl_xor(l, 8);
    float inv = 1.f / l;
    int qi = qrow0 + quad * 4 + r;
#pragma unroll
    for (int dt = 0; dt < 4; ++dt)
      O[base + qi * D_ + dt * 16 + l16] = oacc[dt][r] * inv;
  }
}

extern "C" void kernel_launch(void* const* d_in, const int* in_sizes, int n_in,
                              void* d_out, int out_size, void* d_ws, size_t ws_size,
                              hipStream_t stream) {
  const float* Q  = (const float*)d_in[0];
  const float* K  = (const float*)d_in[1];
  const float* V  = (const float*)d_in[2];
  const int* adj  = (const int*)d_in[3];
  float* O        = (float*)d_out;
  ushort_t* Kf    = (ushort_t*)d_ws;
  ushort_t* Vf    = (ushort_t*)((char*)d_ws + OFF_VF);
  unsigned long long* msk = (unsigned long long*)((char*)d_ws + OFF_MSK);

  prep_kernel<<<2560, 256, 0, stream>>>(K, V, adj, Kf, Vf, msk);
  attn_main<<<1024, 256, 0, stream>>>(Q, Kf, Vf, msk, O);   // 4096 waves: 16/CU
}

// Round 10
// 183.495 us; speedup vs baseline: 1.3800x; 1.0284x over previous
//
#include <hip/hip_runtime.h>
#include <math.h>

typedef short short8 __attribute__((ext_vector_type(8)));
typedef float float4_t __attribute__((ext_vector_type(4)));
typedef unsigned uint2_t __attribute__((ext_vector_type(2)));
typedef unsigned short ushort_t;

#define BH   32
#define N_   2048
#define D_   64
#define NCH  32
#define LDP  72
#define KV_ELEMS (BH * N_ * D_)
// d_ws: Kf [0,8M) | Vf [8M,16M) | msk [16M,16.5M)
#define OFF_VF  (KV_ELEMS * 2)
#define OFF_MSK (KV_ELEMS * 4)
#define QSCALE 0.18033688f      // 0.125*log2(e): exp(s/8) == exp2(s*QSCALE)

__device__ __forceinline__ unsigned pack_bf16(float a, float b) {
  union { float f; unsigned u; } ua{a}, ub{b};
  return __builtin_amdgcn_perm(ub.u + 0x8000u, ua.u + 0x8000u, 0x07060302u);
}

// ---------------- prep (r8-verified, unchanged): fragment-linear Kf/Vf + bitmask ----------------
__global__ __launch_bounds__(256) void prep_kernel(
    const float* __restrict__ K, const float* __restrict__ V,
    const int* __restrict__ adj, ushort_t* __restrict__ Kf,
    ushort_t* __restrict__ Vf, unsigned long long* __restrict__ msk) {
  __shared__ __align__(16) float Tc[64 * 68];
  const int blk = blockIdx.x, t = threadIdx.x;

  if (blk < 2048) {
    const bool isK = blk < 1024;
    const int b = isK ? blk : blk - 1024;
    const float* src = (isK ? K : V) + (b >> 5) * (N_ * D_) + (b & 31) * 64 * D_;
#pragma unroll
    for (int i = 0; i < 4; ++i) {
      int idx = i * 256 + t;
      int row = idx >> 4, c4 = (idx & 15) * 4;
      *(float4_t*)&Tc[row * 68 + c4] = *(const float4_t*)(src + row * D_ + c4);
    }
    __syncthreads();
    ushort_t* dst = (isK ? Kf : Vf) + b * 4096;
#pragma unroll
    for (int e = 0; e < 2; ++e) {
      int u = t * 2 + e;
      int g = u >> 6, lane = u & 63;
      int ks = g >> 2, quad = lane >> 4, l16 = lane & 15;
      float v[8];
      if (isK) {
        int nt = g & 3;
        const float* rp = &Tc[(nt * 16 + l16) * 68 + ks * 32 + quad * 8];
        float4_t a = *(const float4_t*)(rp);
        float4_t bq = *(const float4_t*)(rp + 4);
#pragma unroll
        for (int j = 0; j < 4; ++j) { v[j] = a[j]; v[4 + j] = bq[j]; }
      } else {
        int dt = g & 3, d = dt * 16 + l16;
#pragma unroll
        for (int j = 0; j < 8; ++j) {
          int key = 16 * (j & 3) + ks * 8 + quad * 2 + (j >> 2);
          v[j] = Tc[key * 68 + d];
        }
      }
      union { short8 s; unsigned u4[4]; } h;
      h.u4[0] = pack_bf16(v[0], v[1]); h.u4[1] = pack_bf16(v[2], v[3]);
      h.u4[2] = pack_bf16(v[4], v[5]); h.u4[3] = pack_bf16(v[6], v[7]);
      *(short8*)(dst + u * 8) = h.s;
    }
  } else {
    const int row = (blk - 2048) * 4 + (t >> 6);
    const int lane = t & 63;
    unsigned long long keep = 0;
#pragma unroll 8
    for (int i = 0; i < 32; ++i) {
      int a = adj[row * N_ + i * 64 + lane];
      unsigned long long b = __ballot(a > 0);
      if (lane == i) keep = b;
    }
    if (lane < 32) msk[row * 32 + lane] = keep;
  }
}

// -------- main: barrier-free, 32 rows/wave (2 qg), direct loads, ones-MFMA lsum --------
__global__ __launch_bounds__(256, 2) void attn_main(
    const float* __restrict__ Q, const ushort_t* __restrict__ Kf,
    const ushort_t* __restrict__ Vf, const unsigned long long* __restrict__ msk,
    float* __restrict__ O) {
  __shared__ __align__(16) ushort_t lds_p[4][2][16 * LDP];  // wave-private P

  const int t    = threadIdx.x;
  const int w    = t >> 6;
  const int lane = t & 63;
  const int quad = lane >> 4;
  const int l16  = lane & 15;
  const int bh   = blockIdx.x & (BH - 1);
  const int qt   = blockIdx.x >> 5;          // 0..15
  const int base = bh * (N_ * D_);
  const int qrow0 = qt * 128 + w * 32;       // 32 rows per wave

  const ushort_t* Kfb = Kf + (bh * 32) * 4096;
  const ushort_t* Vfb = Vf + (bh * 32) * 4096;
  const unsigned long long* mr[2] = {
    msk + (qrow0 + quad * 4) * 32,
    msk + (qrow0 + 16 + quad * 4) * 32
  };

  // Q fragments x2 groups, QSCALE folded (A-layout m=l16, k=ks*32+quad*8+j)
  short8 qf[2][2];
#pragma unroll
  for (int qg = 0; qg < 2; ++qg)
#pragma unroll
    for (int ks = 0; ks < 2; ++ks) {
      const float* qp = Q + base + (qrow0 + qg * 16 + l16) * D_ + ks * 32 + quad * 8;
      float4_t f0 = *(const float4_t*)(qp);
      float4_t f1 = *(const float4_t*)(qp + 4);
      union { short8 s; unsigned u[4]; } h;
      h.u[0] = pack_bf16(f0[0] * QSCALE, f0[1] * QSCALE);
      h.u[1] = pack_bf16(f0[2] * QSCALE, f0[3] * QSCALE);
      h.u[2] = pack_bf16(f1[0] * QSCALE, f1[1] * QSCALE);
      h.u[3] = pack_bf16(f1[2] * QSCALE, f1[3] * QSCALE);
      qf[qg][ks] = h.s;
    }

  // constant ones B-fragment (bf16 1.0) for lsum-via-MFMA
  short8 ones;
#pragma unroll
  for (int j = 0; j < 8; ++j) ones[j] = (short)0x3F80;

  float4_t oacc[2][4];    // O, C-layout
  float4_t osum[2];       // row-sums of masked P (all 16 cols identical)
#pragma unroll
  for (int qg = 0; qg < 2; ++qg) {
#pragma unroll
    for (int dt = 0; dt < 4; ++dt) oacc[qg][dt] = (float4_t){0.f, 0.f, 0.f, 0.f};
    osum[qg] = (float4_t){0.f, 0.f, 0.f, 0.f};
  }

  const int fo = lane * 8;   // lane-linear fragment offset (16B/lane coalesced)

  for (int c = 0; c < NCH; ++c) {
    const ushort_t* kg = Kfb + c * 4096;
    const ushort_t* vg = Vfb + c * 4096;

    // issue all chunk loads up front: K frags, V frags, mask words
    short8 kfr[2][4], vfr[2][4];
#pragma unroll
    for (int ks = 0; ks < 2; ++ks)
#pragma unroll
      for (int nt = 0; nt < 4; ++nt) {
        kfr[ks][nt] = *(const short8*)(kg + (ks * 4 + nt) * 512 + fo);
        vfr[ks][nt] = *(const short8*)(vg + (ks * 4 + nt) * 512 + fo);
      }
    unsigned long long mw[2][4];
#pragma unroll
    for (int qg = 0; qg < 2; ++qg)
#pragma unroll
      for (int r = 0; r < 4; ++r) mw[qg][r] = mr[qg][r * 32 + c];

    // ---- per q-group: S-MFMAs -> mask+exp -> P to wave-private LDS ----
#pragma unroll
    for (int qg = 0; qg < 2; ++qg) {
      float4_t sacc[4];
#pragma unroll
      for (int nt = 0; nt < 4; ++nt) sacc[nt] = (float4_t){0.f, 0.f, 0.f, 0.f};
#pragma unroll
      for (int ks = 0; ks < 2; ++ks)
#pragma unroll
        for (int nt = 0; nt < 4; ++nt)
          sacc[nt] = __builtin_amdgcn_mfma_f32_16x16x32_bf16(qf[qg][ks], kfr[ks][nt], sacc[nt], 0, 0, 0);

#pragma unroll
      for (int r = 0; r < 4; ++r) {
        unsigned long long sh = mw[qg][r] >> l16;
        unsigned lo = (unsigned)sh, hi = (unsigned)(sh >> 32);
        float p0 = (lo & 1u)       ? exp2f(sacc[0][r]) : 0.f;
        float p1 = (lo & 0x10000u) ? exp2f(sacc[1][r]) : 0.f;
        float p2 = (hi & 1u)       ? exp2f(sacc[2][r]) : 0.f;
        float p3 = (hi & 0x10000u) ? exp2f(sacc[3][r]) : 0.f;
        uint2_t d2;
        d2.x = pack_bf16(p0, p1);
        d2.y = pack_bf16(p2, p3);
        *(uint2_t*)&lds_p[w][qg][(quad * 4 + r) * LDP + (l16 << 2)] = d2;
      }
    }
    // no barrier: wave-private, ordered by lgkmcnt

    // ---- O += P V ; osum += P * ones ----
#pragma unroll
    for (int qg = 0; qg < 2; ++qg)
#pragma unroll
      for (int ks = 0; ks < 2; ++ks) {
        short8 pf = *(const short8*)&lds_p[w][qg][l16 * LDP + ks * 32 + quad * 8];
#pragma unroll
        for (int dt = 0; dt < 4; ++dt)
          oacc[qg][dt] = __builtin_amdgcn_mfma_f32_16x16x32_bf16(pf, vfr[ks][dt], oacc[qg][dt], 0, 0, 0);
        osum[qg] = __builtin_amdgcn_mfma_f32_16x16x32_bf16(pf, ones, osum[qg], 0, 0, 0);
      }
  }

  // ---- epilogue: rowsum already per-lane in osum (all cols equal) ----
#pragma unroll
  for (int qg = 0; qg < 2; ++qg)
#pragma unroll
    for (int r = 0; r < 4; ++r) {
      float inv = 1.f / osum[qg][r];
      int qi = qrow0 + qg * 16 + quad * 4 + r;
#pragma unroll
      for (int dt = 0; dt < 4; ++dt)
        O[base + qi * D_ + dt * 16 + l16] = oacc[qg][dt][r] * inv;
    }
}

extern "C" void kernel_launch(void* const* d_in, const int* in_sizes, int n_in,
                              void* d_out, int out_size, void* d_ws, size_t ws_size,
                              hipStream_t stream) {
  const float* Q  = (const float*)d_in[0];
  const float* K  = (const float*)d_in[1];
  const float* V  = (const float*)d_in[2];
  const int* adj  = (const int*)d_in[3];
  float* O        = (float*)d_out;
  ushort_t* Kf    = (ushort_t*)d_ws;
  ushort_t* Vf    = (ushort_t*)((char*)d_ws + OFF_VF);
  unsigned long long* msk = (unsigned long long*)((char*)d_ws + OFF_MSK);

  prep_kernel<<<2560, 256, 0, stream>>>(K, V, adj, Kf, Vf, msk);
  attn_main<<<512, 256, 0, stream>>>(Q, Kf, Vf, msk, O);   // 2048 waves, 8/CU
}